// Round 17
// baseline (175.932 us; speedup 1.0000x reference)
//
#include <hip/hip_runtime.h>

#define N_NODES 50000
#define N_EDGES 800000
#define DIM 128
#define NEG_SLOPE 0.01f
#define CAP 32           // bucket capacity
#define OVF_MAX 4096     // overflow list capacity (expected usage: tens)

// ---- range/slice partitioning ----
#define NR 4             // node ranges
#define RNODES 12512     // nodes per range (4*12512 = 50048 >= 50000), LDS 50 KB
#define SLICES 64        // edge slices
#define ESLICE (N_EDGES / SLICES)   // 12500 edges per slice

// ---- bf16 pack/unpack (RNE) ----
__device__ inline unsigned f2b_rne2(float a, float b) {
    unsigned ua = __float_as_uint(a), ub = __float_as_uint(b);
    ua = (ua + 0x7fffu + ((ua >> 16) & 1u)) >> 16;
    ub = (ub + 0x7fffu + ((ub >> 16) & 1u)) >> 16;
    return ua | (ub << 16);
}
__device__ inline float b2f_lo(unsigned u) { return __uint_as_float(u << 16); }
__device__ inline float b2f_hi(unsigned u) { return __uint_as_float(u & 0xffff0000u); }

// ---------------- dual histogram: src + dst per (range, slice), LDS-privatized ----------------
__global__ __launch_bounds__(512) void k_hist2(const int* __restrict__ src,
                                               const int* __restrict__ dst,
                                               int* __restrict__ pSrc, int* __restrict__ pDst) {
    __shared__ int bs[RNODES];             // 50 KB src bins
    __shared__ int bd[RNODES];             // 50 KB dst bins
    int range = blockIdx.x / SLICES;
    int slice = blockIdx.x % SLICES;
    int tid = threadIdx.x;
    for (int j = tid; j < RNODES; j += 512) { bs[j] = 0; bd[j] = 0; }
    __syncthreads();
    int base = range * RNODES;
    const int4* s4 = (const int4*)(src + slice * ESLICE);
    const int4* d4 = (const int4*)(dst + slice * ESLICE);
    for (int t = tid; t < ESLICE / 4; t += 512) {
        int4 v = s4[t];
        unsigned u0 = (unsigned)(v.x - base), u1 = (unsigned)(v.y - base);
        unsigned u2 = (unsigned)(v.z - base), u3 = (unsigned)(v.w - base);
        if (u0 < RNODES) atomicAdd(&bs[u0], 1);
        if (u1 < RNODES) atomicAdd(&bs[u1], 1);
        if (u2 < RNODES) atomicAdd(&bs[u2], 1);
        if (u3 < RNODES) atomicAdd(&bs[u3], 1);
        int4 w = d4[t];
        unsigned w0 = (unsigned)(w.x - base), w1 = (unsigned)(w.y - base);
        unsigned w2 = (unsigned)(w.z - base), w3 = (unsigned)(w.w - base);
        if (w0 < RNODES) atomicAdd(&bd[w0], 1);
        if (w1 < RNODES) atomicAdd(&bd[w1], 1);
        if (w2 < RNODES) atomicAdd(&bd[w2], 1);
        if (w3 < RNODES) atomicAdd(&bd[w3], 1);
    }
    __syncthreads();
    int* os = pSrc + (size_t)blockIdx.x * RNODES;
    int* od = pDst + (size_t)blockIdx.x * RNODES;
    for (int j = tid; j < RNODES; j += 512) { os[j] = bs[j]; od[j] = bd[j]; }
}

// ---------------- scan dst partials (in place) + fused prep + ovf_cnt reset ----------------
__global__ void k_scanprep(const float* __restrict__ weight, const int* __restrict__ sig,
                           const float* __restrict__ emb,
                           const int* __restrict__ pSrc, int* __restrict__ pDst,
                           int* __restrict__ icnt, float* __restrict__ oinv,
                           float* __restrict__ iinv, float* __restrict__ feats3,
                           int* __restrict__ ovf_cnt, int n) {
    int g = blockIdx.x * blockDim.x + threadIdx.x;
    if (g == 0) *ovf_cnt = 0;              // runs before k_fill3 on the stream
    if (g >= NR * RNODES) return;
    int range = g / RNODES, off = g % RNODES;
    size_t basei = (size_t)(range * SLICES) * RNODES + off;
    int run = 0;
    #pragma unroll 8
    for (int s = 0; s < SLICES; ++s) {
        size_t idx = basei + (size_t)s * RNODES;
        int c = pDst[idx];
        pDst[idx] = run;                   // exclusive prefix for slice s
        run += c;
    }
    int od = 0;
    #pragma unroll 8
    for (int s = 0; s < SLICES; ++s) od += pSrc[basei + (size_t)s * RNODES];
    if (g < n) {
        icnt[g] = run;                     // total in-degree
        float oi = 1.0f / sqrtf((float)max(od, 1));
        oinv[g] = oi;
        iinv[g] = 1.0f / sqrtf((float)max(run, 1));
        int sg = sig[g];
        feats3[g * 3 + 0] = weight[g] * oi;
        feats3[g * 3 + 1] = emb[sg * 2 + 0] * oi;
        feats3[g * 3 + 2] = emb[sg * 2 + 1] * oi;
    }
}

// ---------------- atomic-free bucket fill: LDS prefix-cursors ----------------
__global__ __launch_bounds__(512) void k_fill3(const int* __restrict__ src,
                                               const int* __restrict__ dst,
                                               const int* __restrict__ pDst,
                                               unsigned short* __restrict__ eidx,
                                               int* __restrict__ ovf_cnt, int2* __restrict__ ovf) {
    __shared__ int cur[RNODES];            // 50 KB prefix-initialized cursors
    int range = blockIdx.x / SLICES;
    int slice = blockIdx.x % SLICES;
    int tid = threadIdx.x;
    const int* pr = pDst + (size_t)blockIdx.x * RNODES;
    for (int j = tid; j < RNODES; j += 512) cur[j] = pr[j];
    __syncthreads();
    int base = range * RNODES;
    const int* ss = src + slice * ESLICE;
    const int* dd = dst + slice * ESLICE;
    for (int t = tid; t < ESLICE; t += 512) {
        int d = dd[t];
        unsigned u = (unsigned)(d - base);
        if (u < RNODES) {
            int s = ss[t];
            int p = atomicAdd(&cur[u], 1);
            if (p < CAP) eidx[(size_t)d * CAP + p] = (unsigned short)s;
            else { int o = atomicAdd(ovf_cnt, 1); if (o < OVF_MAX) ovf[o] = make_int2(d, s); }
        }
    }
}

// ---------------- fused layer-1: 16 lanes/node, 8 cols/lane; hs row = 16 uint4 ----------------
__global__ void k_aggl1(const int* __restrict__ icnt, const unsigned short* __restrict__ eidx,
                        const float* __restrict__ feats3,
                        const int* __restrict__ ovf_cnt, const int2* __restrict__ ovf,
                        const float* __restrict__ iinv, const float* __restrict__ oinv,
                        const float* __restrict__ W0, const float* __restrict__ b0,
                        uint4* __restrict__ hs, int n) {
    int t = blockIdx.x * blockDim.x + threadIdx.x;
    int i = t >> 4;
    if (i >= n) return;
    int q = t & 15;
    int ic = icnt[i];
    int deg = min(ic, CAP);
    const unsigned short* row = eidx + (size_t)i * CAP;
    float a0 = 0.f, a1 = 0.f, a2 = 0.f;
    for (int k = q; k < deg; k += 16) {
        int s = row[k];
        a0 += feats3[s * 3 + 0];
        a1 += feats3[s * 3 + 1];
        a2 += feats3[s * 3 + 2];
    }
    if (ic > CAP) {                        // rare (~6 nodes): fold overflow edges
        int cnt = min(*ovf_cnt, OVF_MAX);
        for (int e = q; e < cnt; e += 16) {
            int2 ov = ovf[e];              // (dst, src)
            if (ov.x == i) {
                a0 += feats3[ov.y * 3 + 0];
                a1 += feats3[ov.y * 3 + 1];
                a2 += feats3[ov.y * 3 + 2];
            }
        }
    }
    #pragma unroll
    for (int m = 1; m <= 8; m <<= 1) {     // 16-lane butterfly
        a0 += __shfl_xor(a0, m);
        a1 += __shfl_xor(a1, m);
        a2 += __shfl_xor(a2, m);
    }
    float ii = iinv[i], oi = oinv[i];
    a0 *= ii; a1 *= ii; a2 *= ii;
    int j0 = q * 8;
    float v[8];
    #pragma unroll
    for (int c = 0; c < 8; ++c) {
        float x = a0 * W0[j0 + c] + a1 * W0[DIM + j0 + c] + a2 * W0[2 * DIM + j0 + c]
                + b0[j0 + c];
        v[c] = x > 0.f ? x : NEG_SLOPE * x;
    }
    hs[i * 16 + q] = make_uint4(f2b_rne2(v[0] * oi, v[1] * oi),
                                f2b_rne2(v[2] * oi, v[3] * oi),
                                f2b_rne2(v[4] * oi, v[5] * oi),
                                f2b_rne2(v[6] * oi, v[7] * oi));
}

// ---------------- FUSED layer-2: gather (regs) -> sA (LDS) -> @W1 + b1 -> out ----------------
// 256 threads = 16 nodes x 16 lanes. Phase 1: lane q gathers cols 8q..8q+7 of its
// node's neighbor rows (uint4, 8-deep MLP), scales by iinv, stores to sA.
// Phase 2: thread (nn,q) computes out[node][8q..8q+7]: av = sA[nn][k] (LDS
// broadcast, pad 132 -> banks (4nn+k)%32 distinct), W1 row-chunks from global
// (64 KB, L1/L2-hot, 512 B contiguous per wave per k). GEMM hides under gather
// latency of co-resident blocks (~5 blocks/CU: 8.4 KB LDS, no VGPR cap).
#define NPB 16
#define SA_LD 132        // pad: float4-aligned (528 B) and bank-spread
__global__ __launch_bounds__(256) void k_gfinal(
        const int* __restrict__ icnt, const unsigned short* __restrict__ eidx,
        const uint4* __restrict__ hs,
        const int* __restrict__ ovf_cnt, const int2* __restrict__ ovf,
        const float* __restrict__ iinv, const float* __restrict__ W1,
        const float* __restrict__ b1, float* __restrict__ out, int n) {
    __shared__ float sA[NPB][SA_LD];       // 8.25 KB
    int tid = threadIdx.x;
    int q = tid & 15, nn = tid >> 4;
    int i = blockIdx.x * NPB + nn;

    float a0 = 0.f, a1 = 0.f, a2 = 0.f, a3 = 0.f;
    float a4 = 0.f, a5 = 0.f, a6 = 0.f, a7 = 0.f;
    if (i < n) {
        int ic = icnt[i];
        int deg = min(ic, CAP);
        const unsigned short* row = eidx + (size_t)i * CAP;
        int k = 0;
        for (; k + 8 <= deg; k += 8) {
            int s0 = row[k + 0], s1 = row[k + 1], s2 = row[k + 2], s3 = row[k + 3];
            int s4 = row[k + 4], s5 = row[k + 5], s6 = row[k + 6], s7 = row[k + 7];
            uint4 u0 = hs[s0 * 16 + q];
            uint4 u1 = hs[s1 * 16 + q];
            uint4 u2 = hs[s2 * 16 + q];
            uint4 u3 = hs[s3 * 16 + q];
            uint4 u4 = hs[s4 * 16 + q];
            uint4 u5 = hs[s5 * 16 + q];
            uint4 u6 = hs[s6 * 16 + q];
            uint4 u7 = hs[s7 * 16 + q];
            a0 += (b2f_lo(u0.x) + b2f_lo(u1.x)) + (b2f_lo(u2.x) + b2f_lo(u3.x))
                + (b2f_lo(u4.x) + b2f_lo(u5.x)) + (b2f_lo(u6.x) + b2f_lo(u7.x));
            a1 += (b2f_hi(u0.x) + b2f_hi(u1.x)) + (b2f_hi(u2.x) + b2f_hi(u3.x))
                + (b2f_hi(u4.x) + b2f_hi(u5.x)) + (b2f_hi(u6.x) + b2f_hi(u7.x));
            a2 += (b2f_lo(u0.y) + b2f_lo(u1.y)) + (b2f_lo(u2.y) + b2f_lo(u3.y))
                + (b2f_lo(u4.y) + b2f_lo(u5.y)) + (b2f_lo(u6.y) + b2f_lo(u7.y));
            a3 += (b2f_hi(u0.y) + b2f_hi(u1.y)) + (b2f_hi(u2.y) + b2f_hi(u3.y))
                + (b2f_hi(u4.y) + b2f_hi(u5.y)) + (b2f_hi(u6.y) + b2f_hi(u7.y));
            a4 += (b2f_lo(u0.z) + b2f_lo(u1.z)) + (b2f_lo(u2.z) + b2f_lo(u3.z))
                + (b2f_lo(u4.z) + b2f_lo(u5.z)) + (b2f_lo(u6.z) + b2f_lo(u7.z));
            a5 += (b2f_hi(u0.z) + b2f_hi(u1.z)) + (b2f_hi(u2.z) + b2f_hi(u3.z))
                + (b2f_hi(u4.z) + b2f_hi(u5.z)) + (b2f_hi(u6.z) + b2f_hi(u7.z));
            a6 += (b2f_lo(u0.w) + b2f_lo(u1.w)) + (b2f_lo(u2.w) + b2f_lo(u3.w))
                + (b2f_lo(u4.w) + b2f_lo(u5.w)) + (b2f_lo(u6.w) + b2f_lo(u7.w));
            a7 += (b2f_hi(u0.w) + b2f_hi(u1.w)) + (b2f_hi(u2.w) + b2f_hi(u3.w))
                + (b2f_hi(u4.w) + b2f_hi(u5.w)) + (b2f_hi(u6.w) + b2f_hi(u7.w));
        }
        for (; k < deg; ++k) {
            int s = row[k];
            uint4 u = hs[s * 16 + q];
            a0 += b2f_lo(u.x); a1 += b2f_hi(u.x);
            a2 += b2f_lo(u.y); a3 += b2f_hi(u.y);
            a4 += b2f_lo(u.z); a5 += b2f_hi(u.z);
            a6 += b2f_lo(u.w); a7 += b2f_hi(u.w);
        }
        if (ic > CAP) {                    // rare: fold overflow edges
            int cnt = min(*ovf_cnt, OVF_MAX);
            for (int e = 0; e < cnt; ++e) {
                int2 ov = ovf[e];          // (dst, src)
                if (ov.x == i) {
                    uint4 u = hs[ov.y * 16 + q];
                    a0 += b2f_lo(u.x); a1 += b2f_hi(u.x);
                    a2 += b2f_lo(u.y); a3 += b2f_hi(u.y);
                    a4 += b2f_lo(u.z); a5 += b2f_hi(u.z);
                    a6 += b2f_lo(u.w); a7 += b2f_hi(u.w);
                }
            }
        }
        float ii = iinv[i];
        a0 *= ii; a1 *= ii; a2 *= ii; a3 *= ii;
        a4 *= ii; a5 *= ii; a6 *= ii; a7 *= ii;
    }
    *(float4*)&sA[nn][q * 8 + 0] = make_float4(a0, a1, a2, a3);
    *(float4*)&sA[nn][q * 8 + 4] = make_float4(a4, a5, a6, a7);
    __syncthreads();

    // -------- GEMM phase: out[i][8q..8q+7] = sA[nn][:] @ W1[:, 8q..8q+7] + b1 --------
    float c0 = 0.f, c1 = 0.f, c2 = 0.f, c3 = 0.f;
    float c4 = 0.f, c5 = 0.f, c6 = 0.f, c7 = 0.f;
    const float4* W14 = (const float4*)W1;
    #pragma unroll 4
    for (int k = 0; k < DIM; ++k) {
        float av = sA[nn][k];
        float4 w0 = W14[k * 32 + q * 2 + 0];
        float4 w1 = W14[k * 32 + q * 2 + 1];
        c0 += av * w0.x; c1 += av * w0.y; c2 += av * w0.z; c3 += av * w0.w;
        c4 += av * w1.x; c5 += av * w1.y; c6 += av * w1.z; c7 += av * w1.w;
    }
    if (i < n) {
        float4 bb0 = *(const float4*)&b1[q * 8 + 0];
        float4 bb1 = *(const float4*)&b1[q * 8 + 4];
        ((float4*)out)[(size_t)i * 32 + q * 2 + 0] =
            make_float4(c0 + bb0.x, c1 + bb0.y, c2 + bb0.z, c3 + bb0.w);
        ((float4*)out)[(size_t)i * 32 + q * 2 + 1] =
            make_float4(c4 + bb1.x, c5 + bb1.y, c6 + bb1.z, c7 + bb1.w);
    }
}

// ---------------- launch ----------------
extern "C" void kernel_launch(void* const* d_in, const int* in_sizes, int n_in,
                              void* d_out, int out_size, void* d_ws, size_t ws_size,
                              hipStream_t stream) {
    const int*   src  = (const int*)d_in[0];
    const int*   dst  = (const int*)d_in[1];
    const float* weight = (const float*)d_in[2];
    const int*   sig  = (const int*)d_in[3];
    const float* emb  = (const float*)d_in[4];
    const float* W0   = (const float*)d_in[5];
    const float* b0   = (const float*)d_in[6];
    const float* W1   = (const float*)d_in[7];
    const float* b1   = (const float*)d_in[8];
    float* out = (float*)d_out;

    // ---- workspace layout (4B words); no memsets needed ----
    int*   ovf_cnt = (int*)d_ws;                          // @0        8 (zeroed by k_scanprep)
    int2*  ovf     = (int2*)(ovf_cnt + 8);                // @8        4096 int2 (byte %8==0)
    int*   icnt    = (int*)(ovf + OVF_MAX);               // @8200     50000
    float* oinv    = (float*)(icnt + N_NODES);            // @58200    50000
    float* iinv    = oinv + N_NODES;                      // @108200   50000
    float* feats3  = iinv + N_NODES;                      // @158200   150000
    int*   pSrc    = (int*)(feats3 + 3 * N_NODES);        // @308200   3,203,072
    int*   pDst    = pSrc + (size_t)NR * SLICES * RNODES;
    unsigned short* eidx = (unsigned short*)(pDst + (size_t)NR * SLICES * RNODES);
    uint4* hs      = (uint4*)(eidx + (size_t)N_NODES * CAP);  // 16B-aligned

    k_hist2<<<NR * SLICES, 512, 0, stream>>>(src, dst, pSrc, pDst);
    k_scanprep<<<(NR * RNODES + 255) / 256, 256, 0, stream>>>(weight, sig, emb, pSrc, pDst,
                                                              icnt, oinv, iinv, feats3,
                                                              ovf_cnt, N_NODES);
    k_fill3<<<NR * SLICES, 512, 0, stream>>>(src, dst, pDst, eidx, ovf_cnt, ovf);
    k_aggl1<<<(N_NODES * 16 + 255) / 256, 256, 0, stream>>>(icnt, eidx, feats3,
                                                            ovf_cnt, ovf, iinv, oinv,
                                                            W0, b0, hs, N_NODES);
    k_gfinal<<<(N_NODES + NPB - 1) / NPB, 256, 0, stream>>>(icnt, eidx, hs,
                                                            ovf_cnt, ovf, iinv,
                                                            W1, b1, out, N_NODES);
}

// Round 18
// 127.177 us; speedup vs baseline: 1.3834x; 1.3834x over previous
//
#include <hip/hip_runtime.h>

#define N_NODES 50000
#define N_EDGES 800000
#define DIM 128
#define NEG_SLOPE 0.01f
#define CAP 32           // bucket capacity
#define OVF_MAX 4096     // overflow list capacity (expected usage: tens)

// ---- range/slice partitioning ----
#define NR 4             // node ranges
#define RNODES 12512     // nodes per range (4*12512 = 50048 >= 50000), LDS 50 KB
#define SLICES 64        // edge slices
#define ESLICE (N_EDGES / SLICES)   // 12500 edges per slice

// ---- bf16 pack/unpack (RNE) ----
__device__ inline unsigned f2b_rne2(float a, float b) {
    unsigned ua = __float_as_uint(a), ub = __float_as_uint(b);
    ua = (ua + 0x7fffu + ((ua >> 16) & 1u)) >> 16;
    ub = (ub + 0x7fffu + ((ub >> 16) & 1u)) >> 16;
    return ua | (ub << 16);
}
__device__ inline float b2f_lo(unsigned u) { return __uint_as_float(u << 16); }
__device__ inline float b2f_hi(unsigned u) { return __uint_as_float(u & 0xffff0000u); }

// ---------------- dual histogram: src + dst per (range, slice), LDS-privatized ----------------
__global__ __launch_bounds__(512) void k_hist2(const int* __restrict__ src,
                                               const int* __restrict__ dst,
                                               int* __restrict__ pSrc, int* __restrict__ pDst) {
    __shared__ int bs[RNODES];             // 50 KB src bins
    __shared__ int bd[RNODES];             // 50 KB dst bins
    int range = blockIdx.x / SLICES;
    int slice = blockIdx.x % SLICES;
    int tid = threadIdx.x;
    for (int j = tid; j < RNODES; j += 512) { bs[j] = 0; bd[j] = 0; }
    __syncthreads();
    int base = range * RNODES;
    const int4* s4 = (const int4*)(src + slice * ESLICE);
    const int4* d4 = (const int4*)(dst + slice * ESLICE);
    for (int t = tid; t < ESLICE / 4; t += 512) {
        int4 v = s4[t];
        unsigned u0 = (unsigned)(v.x - base), u1 = (unsigned)(v.y - base);
        unsigned u2 = (unsigned)(v.z - base), u3 = (unsigned)(v.w - base);
        if (u0 < RNODES) atomicAdd(&bs[u0], 1);
        if (u1 < RNODES) atomicAdd(&bs[u1], 1);
        if (u2 < RNODES) atomicAdd(&bs[u2], 1);
        if (u3 < RNODES) atomicAdd(&bs[u3], 1);
        int4 w = d4[t];
        unsigned w0 = (unsigned)(w.x - base), w1 = (unsigned)(w.y - base);
        unsigned w2 = (unsigned)(w.z - base), w3 = (unsigned)(w.w - base);
        if (w0 < RNODES) atomicAdd(&bd[w0], 1);
        if (w1 < RNODES) atomicAdd(&bd[w1], 1);
        if (w2 < RNODES) atomicAdd(&bd[w2], 1);
        if (w3 < RNODES) atomicAdd(&bd[w3], 1);
    }
    __syncthreads();
    int* os = pSrc + (size_t)blockIdx.x * RNODES;
    int* od = pDst + (size_t)blockIdx.x * RNODES;
    for (int j = tid; j < RNODES; j += 512) { os[j] = bs[j]; od[j] = bd[j]; }
}

// ---------------- scan dst partials (in place) + fused prep + ovf_cnt reset ----------------
__global__ void k_scanprep(const float* __restrict__ weight, const int* __restrict__ sig,
                           const float* __restrict__ emb,
                           const int* __restrict__ pSrc, int* __restrict__ pDst,
                           int* __restrict__ icnt, float* __restrict__ oinv,
                           float* __restrict__ iinv, float* __restrict__ feats3,
                           int* __restrict__ ovf_cnt, int n) {
    int g = blockIdx.x * blockDim.x + threadIdx.x;
    if (g == 0) *ovf_cnt = 0;              // runs before k_fill3 on the stream
    if (g >= NR * RNODES) return;
    int range = g / RNODES, off = g % RNODES;
    size_t basei = (size_t)(range * SLICES) * RNODES + off;
    int run = 0;
    #pragma unroll 8
    for (int s = 0; s < SLICES; ++s) {
        size_t idx = basei + (size_t)s * RNODES;
        int c = pDst[idx];
        pDst[idx] = run;                   // exclusive prefix for slice s
        run += c;
    }
    int od = 0;
    #pragma unroll 8
    for (int s = 0; s < SLICES; ++s) od += pSrc[basei + (size_t)s * RNODES];
    if (g < n) {
        icnt[g] = run;                     // total in-degree
        float oi = 1.0f / sqrtf((float)max(od, 1));
        oinv[g] = oi;
        iinv[g] = 1.0f / sqrtf((float)max(run, 1));
        int sg = sig[g];
        feats3[g * 3 + 0] = weight[g] * oi;
        feats3[g * 3 + 1] = emb[sg * 2 + 0] * oi;
        feats3[g * 3 + 2] = emb[sg * 2 + 1] * oi;
    }
}

// ---------------- atomic-free bucket fill: LDS prefix-cursors ----------------
__global__ __launch_bounds__(512) void k_fill3(const int* __restrict__ src,
                                               const int* __restrict__ dst,
                                               const int* __restrict__ pDst,
                                               unsigned short* __restrict__ eidx,
                                               int* __restrict__ ovf_cnt, int2* __restrict__ ovf) {
    __shared__ int cur[RNODES];            // 50 KB prefix-initialized cursors
    int range = blockIdx.x / SLICES;
    int slice = blockIdx.x % SLICES;
    int tid = threadIdx.x;
    const int* pr = pDst + (size_t)blockIdx.x * RNODES;
    for (int j = tid; j < RNODES; j += 512) cur[j] = pr[j];
    __syncthreads();
    int base = range * RNODES;
    const int* ss = src + slice * ESLICE;
    const int* dd = dst + slice * ESLICE;
    for (int t = tid; t < ESLICE; t += 512) {
        int d = dd[t];
        unsigned u = (unsigned)(d - base);
        if (u < RNODES) {
            int s = ss[t];
            int p = atomicAdd(&cur[u], 1);
            if (p < CAP) eidx[(size_t)d * CAP + p] = (unsigned short)s;
            else { int o = atomicAdd(ovf_cnt, 1); if (o < OVF_MAX) ovf[o] = make_int2(d, s); }
        }
    }
}

// ---------------- fused layer-1: gather + ovf-fold + (.@W0+b0) + lrelu + bf16 pack ----------------
__global__ void k_aggl1(const int* __restrict__ icnt, const unsigned short* __restrict__ eidx,
                        const float* __restrict__ feats3,
                        const int* __restrict__ ovf_cnt, const int2* __restrict__ ovf,
                        const float* __restrict__ iinv, const float* __restrict__ oinv,
                        const float* __restrict__ W0, const float* __restrict__ b0,
                        unsigned* __restrict__ hs, int n) {
    int t = blockIdx.x * blockDim.x + threadIdx.x;
    int i = t >> 5;
    if (i >= n) return;
    int q = t & 31;
    int ic = icnt[i];
    int deg = min(ic, CAP);
    const unsigned short* row = eidx + (size_t)i * CAP;
    float a0 = 0.f, a1 = 0.f, a2 = 0.f;
    for (int k = q; k < deg; k += 32) {
        int s = row[k];
        a0 += feats3[s * 3 + 0];
        a1 += feats3[s * 3 + 1];
        a2 += feats3[s * 3 + 2];
    }
    if (ic > CAP) {                        // rare (~6 nodes): fold overflow edges
        int cnt = min(*ovf_cnt, OVF_MAX);
        for (int e = q; e < cnt; e += 32) {
            int2 ov = ovf[e];              // (dst, src)
            if (ov.x == i) {
                a0 += feats3[ov.y * 3 + 0];
                a1 += feats3[ov.y * 3 + 1];
                a2 += feats3[ov.y * 3 + 2];
            }
        }
    }
    #pragma unroll
    for (int m = 1; m <= 16; m <<= 1) {
        a0 += __shfl_xor(a0, m);
        a1 += __shfl_xor(a1, m);
        a2 += __shfl_xor(a2, m);
    }
    float ii = iinv[i], oi = oinv[i];
    a0 *= ii; a1 *= ii; a2 *= ii;
    int j0 = q * 4;
    float4 w0r = *(const float4*)&W0[0 * DIM + j0];
    float4 w1r = *(const float4*)&W0[1 * DIM + j0];
    float4 w2r = *(const float4*)&W0[2 * DIM + j0];
    float4 bb  = *(const float4*)&b0[j0];
    float v0 = a0 * w0r.x + a1 * w1r.x + a2 * w2r.x + bb.x;
    float v1 = a0 * w0r.y + a1 * w1r.y + a2 * w2r.y + bb.y;
    float v2 = a0 * w0r.z + a1 * w1r.z + a2 * w2r.z + bb.z;
    float v3 = a0 * w0r.w + a1 * w1r.w + a2 * w2r.w + bb.w;
    v0 = v0 > 0.f ? v0 : NEG_SLOPE * v0;
    v1 = v1 > 0.f ? v1 : NEG_SLOPE * v1;
    v2 = v2 > 0.f ? v2 : NEG_SLOPE * v2;
    v3 = v3 > 0.f ? v3 : NEG_SLOPE * v3;
    ((uint2*)hs)[i * 32 + q] = make_uint2(f2b_rne2(v0 * oi, v1 * oi),
                                          f2b_rne2(v2 * oi, v3 * oi));
}

// ---------------- layer-2 aggregation: bucket gather (8-deep MLP) -> aggbuf ----------------
__global__ void k_gather128(const int* __restrict__ icnt, const unsigned short* __restrict__ eidx,
                            const unsigned* __restrict__ hs,
                            const int* __restrict__ ovf_cnt, const int2* __restrict__ ovf,
                            float* __restrict__ agg, int n) {
    int t = blockIdx.x * blockDim.x + threadIdx.x;
    int i = t >> 5;
    if (i >= n) return;
    int q = t & 31;
    int ic = icnt[i];
    int deg = min(ic, CAP);
    const unsigned short* row = eidx + (size_t)i * CAP;
    const uint2* hs2 = (const uint2*)hs;
    float a0 = 0.f, a1 = 0.f, a2 = 0.f, a3 = 0.f;
    int k = 0;
    for (; k + 8 <= deg; k += 8) {
        int s0 = row[k + 0], s1 = row[k + 1], s2 = row[k + 2], s3 = row[k + 3];
        int s4 = row[k + 4], s5 = row[k + 5], s6 = row[k + 6], s7 = row[k + 7];
        uint2 u0 = hs2[s0 * 32 + q];
        uint2 u1 = hs2[s1 * 32 + q];
        uint2 u2 = hs2[s2 * 32 + q];
        uint2 u3 = hs2[s3 * 32 + q];
        uint2 u4 = hs2[s4 * 32 + q];
        uint2 u5 = hs2[s5 * 32 + q];
        uint2 u6 = hs2[s6 * 32 + q];
        uint2 u7 = hs2[s7 * 32 + q];
        a0 += (b2f_lo(u0.x) + b2f_lo(u1.x)) + (b2f_lo(u2.x) + b2f_lo(u3.x))
            + (b2f_lo(u4.x) + b2f_lo(u5.x)) + (b2f_lo(u6.x) + b2f_lo(u7.x));
        a1 += (b2f_hi(u0.x) + b2f_hi(u1.x)) + (b2f_hi(u2.x) + b2f_hi(u3.x))
            + (b2f_hi(u4.x) + b2f_hi(u5.x)) + (b2f_hi(u6.x) + b2f_hi(u7.x));
        a2 += (b2f_lo(u0.y) + b2f_lo(u1.y)) + (b2f_lo(u2.y) + b2f_lo(u3.y))
            + (b2f_lo(u4.y) + b2f_lo(u5.y)) + (b2f_lo(u6.y) + b2f_lo(u7.y));
        a3 += (b2f_hi(u0.y) + b2f_hi(u1.y)) + (b2f_hi(u2.y) + b2f_hi(u3.y))
            + (b2f_hi(u4.y) + b2f_hi(u5.y)) + (b2f_hi(u6.y) + b2f_hi(u7.y));
    }
    for (; k + 2 <= deg; k += 2) {
        int s0 = row[k], s1 = row[k + 1];
        uint2 u0 = hs2[s0 * 32 + q];
        uint2 u1 = hs2[s1 * 32 + q];
        a0 += b2f_lo(u0.x) + b2f_lo(u1.x);
        a1 += b2f_hi(u0.x) + b2f_hi(u1.x);
        a2 += b2f_lo(u0.y) + b2f_lo(u1.y);
        a3 += b2f_hi(u0.y) + b2f_hi(u1.y);
    }
    if (k < deg) {
        int s = row[k];
        uint2 u = hs2[s * 32 + q];
        a0 += b2f_lo(u.x); a1 += b2f_hi(u.x);
        a2 += b2f_lo(u.y); a3 += b2f_hi(u.y);
    }
    if (ic > CAP) {                        // rare: fold overflow edges
        int cnt = min(*ovf_cnt, OVF_MAX);
        for (int e = 0; e < cnt; ++e) {
            int2 ov = ovf[e];              // (dst, src)
            if (ov.x == i) {
                uint2 u = hs2[ov.y * 32 + q];
                a0 += b2f_lo(u.x); a1 += b2f_hi(u.x);
                a2 += b2f_lo(u.y); a3 += b2f_hi(u.y);
            }
        }
    }
    ((float4*)agg)[i * 32 + q] = make_float4(a0, a1, a2, a3);
}

// ---------------- final: out = (agg * iinv) @ W1 + b1, column-split ----------------
#define FB_NODES 256
__global__ __launch_bounds__(256) void k_final(const float* __restrict__ iinv,
                                               const float* __restrict__ W1,
                                               const float* __restrict__ b1,
                                               const float* __restrict__ agg,
                                               float* __restrict__ out, int n) {
    __shared__ float sW[DIM * 64];         // 32 KB: W1[:, half*64 .. half*64+63]
    int tid = threadIdx.x;
    int half = blockIdx.x & 1;
    int tile = blockIdx.x >> 1;
    for (int idx = tid; idx < DIM * 64 / 4; idx += 256) {
        int r = idx >> 4, c4 = idx & 15;
        *(float4*)&sW[r * 64 + c4 * 4] = *(const float4*)&W1[r * DIM + half * 64 + c4 * 4];
    }
    int cg = tid & 7;                      // 8 col-groups of 8 cols
    int ng = tid >> 3;                     // 32 row-groups of 8 rows
    int col0 = cg * 8;
    int row0 = tile * FB_NODES + ng * 8;

    float acc[8][8];
    #pragma unroll
    for (int i = 0; i < 8; ++i)
        #pragma unroll
        for (int j = 0; j < 8; ++j) acc[i][j] = 0.f;

    __syncthreads();

    const float4* agg4 = (const float4*)agg;
    for (int k4 = 0; k4 < 32; ++k4) {
        float4 a[8];
        #pragma unroll
        for (int i = 0; i < 8; ++i) {
            int r = min(row0 + i, n - 1);          // clamped read; store is guarded
            a[i] = agg4[(size_t)r * 32 + k4];
        }
        #pragma unroll
        for (int kk = 0; kk < 4; ++kk) {
            float4 w0 = *(const float4*)&sW[(k4 * 4 + kk) * 64 + col0];
            float4 w1v = *(const float4*)&sW[(k4 * 4 + kk) * 64 + col0 + 4];
            #pragma unroll
            for (int i = 0; i < 8; ++i) {
                float av = (kk == 0) ? a[i].x : (kk == 1) ? a[i].y : (kk == 2) ? a[i].z : a[i].w;
                acc[i][0] += av * w0.x;  acc[i][1] += av * w0.y;
                acc[i][2] += av * w0.z;  acc[i][3] += av * w0.w;
                acc[i][4] += av * w1v.x; acc[i][5] += av * w1v.y;
                acc[i][6] += av * w1v.z; acc[i][7] += av * w1v.w;
            }
        }
    }

    int gcol = half * 64 + col0;
    float4 bb0 = *(const float4*)&b1[gcol];
    float4 bb1 = *(const float4*)&b1[gcol + 4];
    #pragma unroll
    for (int i = 0; i < 8; ++i) {
        int r = row0 + i;
        if (r < n) {
            float ii = iinv[r];
            float4 o0, o1;
            o0.x = acc[i][0] * ii + bb0.x; o0.y = acc[i][1] * ii + bb0.y;
            o0.z = acc[i][2] * ii + bb0.z; o0.w = acc[i][3] * ii + bb0.w;
            o1.x = acc[i][4] * ii + bb1.x; o1.y = acc[i][5] * ii + bb1.y;
            o1.z = acc[i][6] * ii + bb1.z; o1.w = acc[i][7] * ii + bb1.w;
            ((float4*)out)[(size_t)r * 32 + (gcol >> 2)] = o0;
            ((float4*)out)[(size_t)r * 32 + (gcol >> 2) + 1] = o1;
        }
    }
}

// ---------------- launch ----------------
extern "C" void kernel_launch(void* const* d_in, const int* in_sizes, int n_in,
                              void* d_out, int out_size, void* d_ws, size_t ws_size,
                              hipStream_t stream) {
    const int*   src  = (const int*)d_in[0];
    const int*   dst  = (const int*)d_in[1];
    const float* weight = (const float*)d_in[2];
    const int*   sig  = (const int*)d_in[3];
    const float* emb  = (const float*)d_in[4];
    const float* W0   = (const float*)d_in[5];
    const float* b0   = (const float*)d_in[6];
    const float* W1   = (const float*)d_in[7];
    const float* b1   = (const float*)d_in[8];
    float* out = (float*)d_out;

    // ---- workspace layout (4B words); no memsets needed ----
    int*   ovf_cnt = (int*)d_ws;                          // @0        8 (zeroed by k_scanprep)
    int2*  ovf     = (int2*)(ovf_cnt + 8);                // @8        4096 int2 (byte %8==0)
    int*   icnt    = (int*)(ovf + OVF_MAX);               // @8200     50000
    float* oinv    = (float*)(icnt + N_NODES);            // @58200    50000
    float* iinv    = oinv + N_NODES;                      // @108200   50000
    float* feats3  = iinv + N_NODES;                      // @158200   150000
    int*   pSrc    = (int*)(feats3 + 3 * N_NODES);        // @308200   3,203,072
    int*   pDst    = pSrc + (size_t)NR * SLICES * RNODES;
    unsigned short* eidx = (unsigned short*)(pDst + (size_t)NR * SLICES * RNODES);
    unsigned* hs   = (unsigned*)(eidx + (size_t)N_NODES * CAP);     // 3.2M words
    float* aggbuf  = (float*)(hs + (size_t)N_NODES * 64);           // 6.4M words

    k_hist2<<<NR * SLICES, 512, 0, stream>>>(src, dst, pSrc, pDst);
    k_scanprep<<<(NR * RNODES + 255) / 256, 256, 0, stream>>>(weight, sig, emb, pSrc, pDst,
                                                              icnt, oinv, iinv, feats3,
                                                              ovf_cnt, N_NODES);
    k_fill3<<<NR * SLICES, 512, 0, stream>>>(src, dst, pDst, eidx, ovf_cnt, ovf);
    k_aggl1<<<(N_NODES * 32 + 255) / 256, 256, 0, stream>>>(icnt, eidx, feats3,
                                                            ovf_cnt, ovf, iinv, oinv,
                                                            W0, b0, hs, N_NODES);
    k_gather128<<<((N_NODES * 32) + 255) / 256, 256, 0, stream>>>(icnt, eidx, hs,
                                                                  ovf_cnt, ovf, aggbuf,
                                                                  N_NODES);
    k_final<<<((N_NODES + FB_NODES - 1) / FB_NODES) * 2, 256, 0, stream>>>(
        iinv, W1, b1, aggbuf, out, N_NODES);
}